// Round 1
// baseline (4793.111 us; speedup 1.0000x reference)
//
#include <hip/hip_runtime.h>
#include <hip/hip_bf16.h>

#define NN 100000
#define NE 600000

// ---------- helpers ----------
__device__ __forceinline__ float b2f(unsigned short u) {
  unsigned int v = ((unsigned int)u) << 16;
  return __uint_as_float(v);
}
__device__ __forceinline__ unsigned short f2b(float f) {
  __hip_bfloat16 h = __float2bfloat16(f);  // RNE
  return *reinterpret_cast<unsigned short*>(&h);
}
__device__ __forceinline__ float elu(float v) {
  return v > 0.0f ? v : (expf(v) - 1.0f);
}

// ---------- aggregation layer 1: x[src] (128 f32) -> sums1[dst], cnt[dst] ----------
__global__ __launch_bounds__(256) void agg1_kernel(
    const float* __restrict__ x, const int* __restrict__ ei,
    float* __restrict__ sums, float* __restrict__ cnt) {
  const int* src = ei;
  const int* dst = ei + NE;
  int lane = threadIdx.x & 63;
  int wid  = (blockIdx.x * 256 + threadIdx.x) >> 6;
  int nw   = gridDim.x * 4;
  for (int e = wid; e < NE; e += nw) {
    int s = src[e], d = dst[e];
    const float* xr = x + (size_t)s * 128;
    float v0 = xr[lane];
    float v1 = xr[lane + 64];
    float* sr = sums + (size_t)d * 128;
    unsafeAtomicAdd(sr + lane, v0);
    unsafeAtomicAdd(sr + lane + 64, v1);
    if (lane == 0) unsafeAtomicAdd(cnt + d, 1.0f);
  }
}

// ---------- aggregation layer 2: h1[src] (256 bf16) -> sums2[dst] ----------
__global__ __launch_bounds__(256) void agg2_kernel(
    const unsigned short* __restrict__ h, const int* __restrict__ ei,
    float* __restrict__ sums) {
  const int* src = ei;
  const int* dst = ei + NE;
  int lane = threadIdx.x & 63;
  int wid  = (blockIdx.x * 256 + threadIdx.x) >> 6;
  int nw   = gridDim.x * 4;
  for (int e = wid; e < NE; e += nw) {
    int s = src[e], d = dst[e];
    ushort4 u = ((const ushort4*)(h + (size_t)s * 256))[lane];
    float* sr = sums + (size_t)d * 256 + lane * 4;
    unsafeAtomicAdd(sr + 0, b2f(u.x));
    unsafeAtomicAdd(sr + 1, b2f(u.y));
    unsafeAtomicAdd(sr + 2, b2f(u.z));
    unsafeAtomicAdd(sr + 3, b2f(u.w));
  }
}

// ---------- layer 1 dense: h1 = ELU(mean1 @ W1l^T + b1 + x @ W1r^T), K=128 ----------
__global__ __launch_bounds__(256) void layer1_kernel(
    const float* __restrict__ x, const float* __restrict__ sums,
    const float* __restrict__ cnt,
    const float* __restrict__ Wl, const float* __restrict__ b,
    const float* __restrict__ Wr, unsigned short* __restrict__ hout) {
  __shared__ float sm[8][128];
  __shared__ float sx[8][128];
  int t  = threadIdx.x;
  int n0 = blockIdx.x * 8;
  {
    int r = t >> 5, k4 = t & 31;   // 8 rows x 32 float4 = 256 slots
    int n = n0 + r;
    float inv = 1.0f / fmaxf(cnt[n], 1.0f);
    float4 s4 = ((const float4*)(sums + (size_t)n * 128))[k4];
    float4 x4 = ((const float4*)(x + (size_t)n * 128))[k4];
    ((float4*)&sm[r][0])[k4] = make_float4(s4.x * inv, s4.y * inv, s4.z * inv, s4.w * inv);
    ((float4*)&sx[r][0])[k4] = x4;
  }
  __syncthreads();
  int j = t;  // output column
  float acc[8] = {0, 0, 0, 0, 0, 0, 0, 0};
  const float4* wl = (const float4*)(Wl + (size_t)j * 128);
  const float4* wr = (const float4*)(Wr + (size_t)j * 128);
#pragma unroll 8
  for (int k4 = 0; k4 < 32; ++k4) {
    float4 a = wl[k4];
    float4 c = wr[k4];
#pragma unroll
    for (int r = 0; r < 8; ++r) {
      float4 m4 = ((const float4*)&sm[r][0])[k4];
      float4 x4 = ((const float4*)&sx[r][0])[k4];
      float acv = acc[r];
      acv = fmaf(m4.x, a.x, acv); acv = fmaf(m4.y, a.y, acv);
      acv = fmaf(m4.z, a.z, acv); acv = fmaf(m4.w, a.w, acv);
      acv = fmaf(x4.x, c.x, acv); acv = fmaf(x4.y, c.y, acv);
      acv = fmaf(x4.z, c.z, acv); acv = fmaf(x4.w, c.w, acv);
      acc[r] = acv;
    }
  }
  float bias = b[j];
#pragma unroll
  for (int r = 0; r < 8; ++r) {
    hout[(size_t)(n0 + r) * 256 + j] = f2b(elu(acc[r] + bias));
  }
}

// ---------- layer 2 dense: h2 = ELU(mean2 @ W2l^T + b2 + h1 @ W2r^T), K=256 ----------
__global__ __launch_bounds__(256) void layer2_kernel(
    const unsigned short* __restrict__ hin, const float* __restrict__ sums,
    const float* __restrict__ cnt,
    const float* __restrict__ Wl, const float* __restrict__ b,
    const float* __restrict__ Wr, unsigned short* __restrict__ hout) {
  __shared__ float sm[8][256];
  __shared__ float sx[8][256];
  int t  = threadIdx.x;
  int n0 = blockIdx.x * 8;
#pragma unroll
  for (int i = 0; i < 2; ++i) {
    int idx = t + i * 256;         // 512 vec4 slots
    int r = idx >> 6, k4 = idx & 63;
    int n = n0 + r;
    float inv = 1.0f / fmaxf(cnt[n], 1.0f);
    float4 s4 = ((const float4*)(sums + (size_t)n * 256))[k4];
    ushort4 u = ((const ushort4*)(hin + (size_t)n * 256))[k4];
    ((float4*)&sm[r][0])[k4] = make_float4(s4.x * inv, s4.y * inv, s4.z * inv, s4.w * inv);
    ((float4*)&sx[r][0])[k4] = make_float4(b2f(u.x), b2f(u.y), b2f(u.z), b2f(u.w));
  }
  __syncthreads();
  int j = t;
  float acc[8] = {0, 0, 0, 0, 0, 0, 0, 0};
  const float4* wl = (const float4*)(Wl + (size_t)j * 256);
  const float4* wr = (const float4*)(Wr + (size_t)j * 256);
#pragma unroll 8
  for (int k4 = 0; k4 < 64; ++k4) {
    float4 a = wl[k4];
    float4 c = wr[k4];
#pragma unroll
    for (int r = 0; r < 8; ++r) {
      float4 m4 = ((const float4*)&sm[r][0])[k4];
      float4 x4 = ((const float4*)&sx[r][0])[k4];
      float acv = acc[r];
      acv = fmaf(m4.x, a.x, acv); acv = fmaf(m4.y, a.y, acv);
      acv = fmaf(m4.z, a.z, acv); acv = fmaf(m4.w, a.w, acv);
      acv = fmaf(x4.x, c.x, acv); acv = fmaf(x4.y, c.y, acv);
      acv = fmaf(x4.z, c.z, acv); acv = fmaf(x4.w, c.w, acv);
      acc[r] = acv;
    }
  }
  float bias = b[j];
#pragma unroll
  for (int r = 0; r < 8; ++r) {
    hout[(size_t)(n0 + r) * 256 + j] = f2b(elu(acc[r] + bias));
  }
}

// ---------- fused MLP head: out = relu(h2 @ Wf1^T + bf1) @ Wf2^T + bf2 ----------
__global__ __launch_bounds__(256) void head_kernel(
    const unsigned short* __restrict__ h, const float* __restrict__ W1,
    const float* __restrict__ b1, const float* __restrict__ W2,
    const float* __restrict__ b2, float* __restrict__ out) {
  __shared__ float sh[4][256];
  int wv = threadIdx.x >> 6, lane = threadIdx.x & 63;
  int n = blockIdx.x * 4 + wv;
  ushort4 u = ((const ushort4*)(h + (size_t)n * 256))[lane];
  ((float4*)&sh[wv][0])[lane] = make_float4(b2f(u.x), b2f(u.y), b2f(u.z), b2f(u.w));
  __syncthreads();
  float acc0 = 0.0f, acc1 = 0.0f;
  const float4* w0 = (const float4*)(W1 + (size_t)lane * 256);
  const float4* w1 = (const float4*)(W1 + (size_t)(lane + 64) * 256);
#pragma unroll 8
  for (int k4 = 0; k4 < 64; ++k4) {
    float4 hv = ((const float4*)&sh[wv][0])[k4];
    float4 a = w0[k4];
    float4 c = w1[k4];
    acc0 = fmaf(hv.x, a.x, acc0); acc0 = fmaf(hv.y, a.y, acc0);
    acc0 = fmaf(hv.z, a.z, acc0); acc0 = fmaf(hv.w, a.w, acc0);
    acc1 = fmaf(hv.x, c.x, acc1); acc1 = fmaf(hv.y, c.y, acc1);
    acc1 = fmaf(hv.z, c.z, acc1); acc1 = fmaf(hv.w, c.w, acc1);
  }
  float v = fmaxf(acc0 + b1[lane], 0.0f) * W2[lane]
          + fmaxf(acc1 + b1[lane + 64], 0.0f) * W2[lane + 64];
#pragma unroll
  for (int off = 32; off > 0; off >>= 1) v += __shfl_down(v, off);
  if (lane == 0) out[n] = v + b2[0];
}

extern "C" void kernel_launch(void* const* d_in, const int* in_sizes, int n_in,
                              void* d_out, int out_size, void* d_ws, size_t ws_size,
                              hipStream_t stream) {
  const float* x   = (const float*)d_in[0];
  const int*   ei  = (const int*)d_in[1];
  const float* W1l = (const float*)d_in[2];
  const float* b1  = (const float*)d_in[3];
  const float* W1r = (const float*)d_in[4];
  const float* W2l = (const float*)d_in[5];
  const float* b2  = (const float*)d_in[6];
  const float* W2r = (const float*)d_in[7];
  const float* Wf1 = (const float*)d_in[8];
  const float* bf1 = (const float*)d_in[9];
  const float* Wf2 = (const float*)d_in[10];
  const float* bf2 = (const float*)d_in[11];
  float* out = (float*)d_out;

  char* ws = (char*)d_ws;
  size_t o = 0;
  float* cnt   = (float*)(ws + o); o += 400384;                 // N f32 (padded)
  float* sums1 = (float*)(ws + o); o += (size_t)NN * 128 * 4;   // 51.2 MB
  float* sums2 = (float*)(ws + o); o += (size_t)NN * 256 * 4;   // 102.4 MB
  size_t zero_bytes = o;
  unsigned short* h1 = (unsigned short*)(ws + o); o += (size_t)NN * 256 * 2;  // bf16
  unsigned short* h2 = (unsigned short*)(ws + o); o += (size_t)NN * 256 * 2;  // bf16

  // ws is NOT re-poisoned between replays: zero accumulators every call.
  hipMemsetAsync(d_ws, 0, zero_bytes, stream);

  agg1_kernel<<<4096, 256, 0, stream>>>(x, ei, sums1, cnt);
  layer1_kernel<<<NN / 8, 256, 0, stream>>>(x, sums1, cnt, W1l, b1, W1r, h1);
  agg2_kernel<<<4096, 256, 0, stream>>>(h1, ei, sums2);
  layer2_kernel<<<NN / 8, 256, 0, stream>>>(h1, sums2, cnt, W2l, b2, W2r, h2);
  head_kernel<<<NN / 4, 256, 0, stream>>>(h2, Wf1, bf1, Wf2, bf2, out);
}

// Round 2
// 2638.557 us; speedup vs baseline: 1.8166x; 1.8166x over previous
//
#include <hip/hip_runtime.h>
#include <hip/hip_bf16.h>

#define NN 100000
#define NE 600000
#define NBLK 98  // ceil(NN/1024) for the scan

// ---------- helpers ----------
__device__ __forceinline__ float b2f(unsigned short u) {
  unsigned int v = ((unsigned int)u) << 16;
  return __uint_as_float(v);
}
__device__ __forceinline__ unsigned short f2b(float f) {
  __hip_bfloat16 h = __float2bfloat16(f);  // RNE
  return *reinterpret_cast<unsigned short*>(&h);
}
__device__ __forceinline__ float elu(float v) {
  return v > 0.0f ? v : (expf(v) - 1.0f);
}

// ================= CSR build (by destination) =================
__global__ __launch_bounds__(256) void hist_kernel(
    const int* __restrict__ ei, int* __restrict__ deg) {
  const int* dst = ei + NE;
  int i = blockIdx.x * 256 + threadIdx.x;
  int n = gridDim.x * 256;
  for (int e = i; e < NE; e += n) atomicAdd(&deg[dst[e]], 1);
}

// per-block (1024 elems) exclusive scan; block totals -> aux
__global__ __launch_bounds__(256) void scan1_kernel(
    const int* __restrict__ deg, int* __restrict__ row, int* __restrict__ aux) {
  __shared__ int sd[256];
  int b = blockIdx.x, t = threadIdx.x;
  int base = b * 1024 + t * 4;
  int v0 = (base + 0 < NN) ? deg[base + 0] : 0;
  int v1 = (base + 1 < NN) ? deg[base + 1] : 0;
  int v2 = (base + 2 < NN) ? deg[base + 2] : 0;
  int v3 = (base + 3 < NN) ? deg[base + 3] : 0;
  int s = v0 + v1 + v2 + v3;
  sd[t] = s;
  __syncthreads();
  for (int off = 1; off < 256; off <<= 1) {
    int tmp = (t >= off) ? sd[t - off] : 0;
    __syncthreads();
    sd[t] += tmp;
    __syncthreads();
  }
  int excl = sd[t] - s;
  if (base + 0 < NN) row[base + 0] = excl;
  if (base + 1 < NN) row[base + 1] = excl + v0;
  if (base + 2 < NN) row[base + 2] = excl + v0 + v1;
  if (base + 3 < NN) row[base + 3] = excl + v0 + v1 + v2;
  if (t == 255) aux[b] = sd[t];
}

// single-block exclusive scan of the block totals
__global__ __launch_bounds__(256) void scan2_kernel(int* __restrict__ aux) {
  __shared__ int sd[256];
  int t = threadIdx.x;
  int v = (t < NBLK) ? aux[t] : 0;
  sd[t] = v;
  __syncthreads();
  for (int off = 1; off < 256; off <<= 1) {
    int tmp = (t >= off) ? sd[t - off] : 0;
    __syncthreads();
    sd[t] += tmp;
    __syncthreads();
  }
  if (t < NBLK) aux[t] = sd[t] - v;
}

__global__ __launch_bounds__(256) void scan3_kernel(
    int* __restrict__ row, const int* __restrict__ aux) {
  int i = blockIdx.x * 256 + threadIdx.x;
  if (i < NN) row[i] += aux[i >> 10];
  if (i == 0) row[NN] = NE;
}

__global__ __launch_bounds__(256) void fill_kernel(
    const int* __restrict__ ei, const int* __restrict__ row,
    int* __restrict__ cur, int* __restrict__ eidx) {
  const int* src = ei;
  const int* dst = ei + NE;
  int i = blockIdx.x * 256 + threadIdx.x;
  int n = gridDim.x * 256;
  for (int e = i; e < NE; e += n) {
    int d = dst[e];
    int p = atomicAdd(&cur[d], 1);
    eidx[row[d] + p] = src[e];
  }
}

// ================= aggregation via CSR gather (no float atomics) ==========
// one wave per destination node; 128 f32 = float2/lane
__global__ __launch_bounds__(256) void agg1_csr(
    const float* __restrict__ x, const int* __restrict__ row,
    const int* __restrict__ eidx, float* __restrict__ mean1) {
  int lane = threadIdx.x & 63;
  int n = (blockIdx.x * 256 + threadIdx.x) >> 6;
  if (n >= NN) return;
  int r0 = row[n], r1 = row[n + 1];
  float2 acc = make_float2(0.f, 0.f);
  int e = r0;
  for (; e + 1 < r1; e += 2) {
    int s0 = eidx[e], s1 = eidx[e + 1];
    float2 a = ((const float2*)(x + (size_t)s0 * 128))[lane];
    float2 b = ((const float2*)(x + (size_t)s1 * 128))[lane];
    acc.x += a.x + b.x;
    acc.y += a.y + b.y;
  }
  if (e < r1) {
    int s0 = eidx[e];
    float2 a = ((const float2*)(x + (size_t)s0 * 128))[lane];
    acc.x += a.x;
    acc.y += a.y;
  }
  float inv = 1.0f / (float)max(r1 - r0, 1);
  ((float2*)(mean1 + (size_t)n * 128))[lane] = make_float2(acc.x * inv, acc.y * inv);
}

// one wave per destination node; 256 bf16 = ushort4/lane; mean stored bf16
__global__ __launch_bounds__(256) void agg2_csr(
    const unsigned short* __restrict__ h, const int* __restrict__ row,
    const int* __restrict__ eidx, unsigned short* __restrict__ mean2) {
  int lane = threadIdx.x & 63;
  int n = (blockIdx.x * 256 + threadIdx.x) >> 6;
  if (n >= NN) return;
  int r0 = row[n], r1 = row[n + 1];
  float4 acc = make_float4(0.f, 0.f, 0.f, 0.f);
  int e = r0;
  for (; e + 1 < r1; e += 2) {
    int s0 = eidx[e], s1 = eidx[e + 1];
    ushort4 a = ((const ushort4*)(h + (size_t)s0 * 256))[lane];
    ushort4 b = ((const ushort4*)(h + (size_t)s1 * 256))[lane];
    acc.x += b2f(a.x) + b2f(b.x);
    acc.y += b2f(a.y) + b2f(b.y);
    acc.z += b2f(a.z) + b2f(b.z);
    acc.w += b2f(a.w) + b2f(b.w);
  }
  if (e < r1) {
    int s0 = eidx[e];
    ushort4 a = ((const ushort4*)(h + (size_t)s0 * 256))[lane];
    acc.x += b2f(a.x);
    acc.y += b2f(a.y);
    acc.z += b2f(a.z);
    acc.w += b2f(a.w);
  }
  float inv = 1.0f / (float)max(r1 - r0, 1);
  ushort4 o;
  o.x = f2b(acc.x * inv);
  o.y = f2b(acc.y * inv);
  o.z = f2b(acc.z * inv);
  o.w = f2b(acc.w * inv);
  ((ushort4*)(mean2 + (size_t)n * 256))[lane] = o;
}

// ---------- layer 1 dense: h1 = ELU(mean1 @ W1l^T + b1 + x @ W1r^T), K=128 ----
__global__ __launch_bounds__(256) void layer1_kernel(
    const float* __restrict__ x, const float* __restrict__ mean1,
    const float* __restrict__ Wl, const float* __restrict__ b,
    const float* __restrict__ Wr, unsigned short* __restrict__ hout) {
  __shared__ float sm[8][128];
  __shared__ float sx[8][128];
  int t  = threadIdx.x;
  int n0 = blockIdx.x * 8;
  {
    int r = t >> 5, k4 = t & 31;   // 8 rows x 32 float4 = 256 slots
    int n = n0 + r;
    float4 s4 = ((const float4*)(mean1 + (size_t)n * 128))[k4];
    float4 x4 = ((const float4*)(x + (size_t)n * 128))[k4];
    ((float4*)&sm[r][0])[k4] = s4;
    ((float4*)&sx[r][0])[k4] = x4;
  }
  __syncthreads();
  int j = t;  // output column
  float acc[8] = {0, 0, 0, 0, 0, 0, 0, 0};
  const float4* wl = (const float4*)(Wl + (size_t)j * 128);
  const float4* wr = (const float4*)(Wr + (size_t)j * 128);
#pragma unroll 8
  for (int k4 = 0; k4 < 32; ++k4) {
    float4 a = wl[k4];
    float4 c = wr[k4];
#pragma unroll
    for (int r = 0; r < 8; ++r) {
      float4 m4 = ((const float4*)&sm[r][0])[k4];
      float4 x4 = ((const float4*)&sx[r][0])[k4];
      float acv = acc[r];
      acv = fmaf(m4.x, a.x, acv); acv = fmaf(m4.y, a.y, acv);
      acv = fmaf(m4.z, a.z, acv); acv = fmaf(m4.w, a.w, acv);
      acv = fmaf(x4.x, c.x, acv); acv = fmaf(x4.y, c.y, acv);
      acv = fmaf(x4.z, c.z, acv); acv = fmaf(x4.w, c.w, acv);
      acc[r] = acv;
    }
  }
  float bias = b[j];
#pragma unroll
  for (int r = 0; r < 8; ++r) {
    hout[(size_t)(n0 + r) * 256 + j] = f2b(elu(acc[r] + bias));
  }
}

// ---------- layer 2 dense: h2 = ELU(mean2 @ W2l^T + b2 + h1 @ W2r^T), K=256 ----
__global__ __launch_bounds__(256) void layer2_kernel(
    const unsigned short* __restrict__ hin, const unsigned short* __restrict__ mean2,
    const float* __restrict__ Wl, const float* __restrict__ b,
    const float* __restrict__ Wr, unsigned short* __restrict__ hout) {
  __shared__ float sm[8][256];
  __shared__ float sx[8][256];
  int t  = threadIdx.x;
  int n0 = blockIdx.x * 8;
#pragma unroll
  for (int i = 0; i < 2; ++i) {
    int idx = t + i * 256;         // 512 vec4 slots
    int r = idx >> 6, k4 = idx & 63;
    int n = n0 + r;
    ushort4 m = ((const ushort4*)(mean2 + (size_t)n * 256))[k4];
    ushort4 u = ((const ushort4*)(hin + (size_t)n * 256))[k4];
    ((float4*)&sm[r][0])[k4] = make_float4(b2f(m.x), b2f(m.y), b2f(m.z), b2f(m.w));
    ((float4*)&sx[r][0])[k4] = make_float4(b2f(u.x), b2f(u.y), b2f(u.z), b2f(u.w));
  }
  __syncthreads();
  int j = t;
  float acc[8] = {0, 0, 0, 0, 0, 0, 0, 0};
  const float4* wl = (const float4*)(Wl + (size_t)j * 256);
  const float4* wr = (const float4*)(Wr + (size_t)j * 256);
#pragma unroll 8
  for (int k4 = 0; k4 < 64; ++k4) {
    float4 a = wl[k4];
    float4 c = wr[k4];
#pragma unroll
    for (int r = 0; r < 8; ++r) {
      float4 m4 = ((const float4*)&sm[r][0])[k4];
      float4 x4 = ((const float4*)&sx[r][0])[k4];
      float acv = acc[r];
      acv = fmaf(m4.x, a.x, acv); acv = fmaf(m4.y, a.y, acv);
      acv = fmaf(m4.z, a.z, acv); acv = fmaf(m4.w, a.w, acv);
      acv = fmaf(x4.x, c.x, acv); acv = fmaf(x4.y, c.y, acv);
      acv = fmaf(x4.z, c.z, acv); acv = fmaf(x4.w, c.w, acv);
      acc[r] = acv;
    }
  }
  float bias = b[j];
#pragma unroll
  for (int r = 0; r < 8; ++r) {
    hout[(size_t)(n0 + r) * 256 + j] = f2b(elu(acc[r] + bias));
  }
}

// ---------- fused MLP head: out = relu(h2 @ Wf1^T + bf1) @ Wf2^T + bf2 ----------
__global__ __launch_bounds__(256) void head_kernel(
    const unsigned short* __restrict__ h, const float* __restrict__ W1,
    const float* __restrict__ b1, const float* __restrict__ W2,
    const float* __restrict__ b2, float* __restrict__ out) {
  __shared__ float sh[4][256];
  int wv = threadIdx.x >> 6, lane = threadIdx.x & 63;
  int n = blockIdx.x * 4 + wv;
  ushort4 u = ((const ushort4*)(h + (size_t)n * 256))[lane];
  ((float4*)&sh[wv][0])[lane] = make_float4(b2f(u.x), b2f(u.y), b2f(u.z), b2f(u.w));
  __syncthreads();
  float acc0 = 0.0f, acc1 = 0.0f;
  const float4* w0 = (const float4*)(W1 + (size_t)lane * 256);
  const float4* w1 = (const float4*)(W1 + (size_t)(lane + 64) * 256);
#pragma unroll 8
  for (int k4 = 0; k4 < 64; ++k4) {
    float4 hv = ((const float4*)&sh[wv][0])[k4];
    float4 a = w0[k4];
    float4 c = w1[k4];
    acc0 = fmaf(hv.x, a.x, acc0); acc0 = fmaf(hv.y, a.y, acc0);
    acc0 = fmaf(hv.z, a.z, acc0); acc0 = fmaf(hv.w, a.w, acc0);
    acc1 = fmaf(hv.x, c.x, acc1); acc1 = fmaf(hv.y, c.y, acc1);
    acc1 = fmaf(hv.z, c.z, acc1); acc1 = fmaf(hv.w, c.w, acc1);
  }
  float v = fmaxf(acc0 + b1[lane], 0.0f) * W2[lane]
          + fmaxf(acc1 + b1[lane + 64], 0.0f) * W2[lane + 64];
#pragma unroll
  for (int off = 32; off > 0; off >>= 1) v += __shfl_down(v, off);
  if (lane == 0) out[n] = v + b2[0];
}

extern "C" void kernel_launch(void* const* d_in, const int* in_sizes, int n_in,
                              void* d_out, int out_size, void* d_ws, size_t ws_size,
                              hipStream_t stream) {
  const float* x   = (const float*)d_in[0];
  const int*   ei  = (const int*)d_in[1];
  const float* W1l = (const float*)d_in[2];
  const float* b1  = (const float*)d_in[3];
  const float* W1r = (const float*)d_in[4];
  const float* W2l = (const float*)d_in[5];
  const float* b2  = (const float*)d_in[6];
  const float* W2r = (const float*)d_in[7];
  const float* Wf1 = (const float*)d_in[8];
  const float* bf1 = (const float*)d_in[9];
  const float* Wf2 = (const float*)d_in[10];
  const float* bf2 = (const float*)d_in[11];
  float* out = (float*)d_out;

  char* ws = (char*)d_ws;
  size_t o = 0;
  int* deg = (int*)(ws + o); o += 400384;   // NN ints, padded to 256B
  int* cur = (int*)(ws + o); o += 400384;
  size_t zero_bytes = o;                    // only deg+cur need zeroing
  int* row  = (int*)(ws + o); o += 400640;  // NN+1 ints
  int* aux  = (int*)(ws + o); o += 4096;
  int* eidx = (int*)(ws + o); o += 2400000; // NE ints
  float*          mean1 = (float*)(ws + o);          o += (size_t)NN * 128 * 4;
  unsigned short* mean2 = (unsigned short*)(ws + o); o += (size_t)NN * 256 * 2;
  unsigned short* h1    = (unsigned short*)(ws + o); o += (size_t)NN * 256 * 2;
  unsigned short* h2    = (unsigned short*)(ws + o); o += (size_t)NN * 256 * 2;
  // total ~208 MB

  // ws is NOT re-poisoned between replays: zero the histogram/cursor each call.
  hipMemsetAsync(d_ws, 0, zero_bytes, stream);

  // CSR build (deterministic per call)
  hist_kernel<<<2048, 256, 0, stream>>>(ei, deg);
  scan1_kernel<<<NBLK, 256, 0, stream>>>(deg, row, aux);
  scan2_kernel<<<1, 256, 0, stream>>>(aux);
  scan3_kernel<<<(NN + 255) / 256, 256, 0, stream>>>(row, aux);
  fill_kernel<<<2048, 256, 0, stream>>>(ei, row, cur, eidx);

  // pipeline
  agg1_csr<<<25000, 256, 0, stream>>>(x, row, eidx, mean1);
  layer1_kernel<<<NN / 8, 256, 0, stream>>>(x, mean1, W1l, b1, W1r, h1);
  agg2_csr<<<25000, 256, 0, stream>>>(h1, row, eidx, mean2);
  layer2_kernel<<<NN / 8, 256, 0, stream>>>(h1, mean2, W2l, b2, W2r, h2);
  head_kernel<<<NN / 4, 256, 0, stream>>>(h2, Wf1, bf1, Wf2, bf2, out);
}

// Round 3
// 337.498 us; speedup vs baseline: 14.2019x; 7.8180x over previous
//
#include <hip/hip_runtime.h>
#include <hip/hip_bf16.h>

#define NN 100000
#define NE 600000
#define NBLK 98            // ceil(NN/1024) for the scan
#define MPAD 100096        // 782 * 128

typedef __attribute__((ext_vector_type(4))) int   i32x4;
typedef __attribute__((ext_vector_type(4))) float f32x4;

// ---------- helpers ----------
__device__ __forceinline__ float b2f(unsigned short u) {
  unsigned int v = ((unsigned int)u) << 16;
  return __uint_as_float(v);
}
__device__ __forceinline__ unsigned short f2b(float f) {
  __hip_bfloat16 h = __float2bfloat16(f);  // RNE
  return *reinterpret_cast<unsigned short*>(&h);
}
__device__ __forceinline__ float elu(float v) {
  return v > 0.0f ? v : (expf(v) - 1.0f);
}
__device__ __forceinline__ void gload_lds16(const void* g, void* l) {
  __builtin_amdgcn_global_load_lds(
      (const __attribute__((address_space(1))) void*)g,
      (__attribute__((address_space(3))) void*)l, 16, 0, 0);
}
__device__ __forceinline__ f32x4 mfma16(i32x4 a, i32x4 b, f32x4 c) {
  asm volatile("v_mfma_f32_16x16x32_bf16 %0, %1, %2, %0"
               : "+v"(c) : "v"(a), "v"(b));
  return c;
}

// ================= CSR build (by destination) =================
__global__ __launch_bounds__(256) void hist_kernel(
    const int* __restrict__ ei, int* __restrict__ deg) {
  const int* dst = ei + NE;
  int i = blockIdx.x * 256 + threadIdx.x;
  int n = gridDim.x * 256;
  for (int e = i; e < NE; e += n) atomicAdd(&deg[dst[e]], 1);
}

__global__ __launch_bounds__(256) void scan1_kernel(
    const int* __restrict__ deg, int* __restrict__ row, int* __restrict__ aux) {
  __shared__ int sd[256];
  int b = blockIdx.x, t = threadIdx.x;
  int base = b * 1024 + t * 4;
  int v0 = (base + 0 < NN) ? deg[base + 0] : 0;
  int v1 = (base + 1 < NN) ? deg[base + 1] : 0;
  int v2 = (base + 2 < NN) ? deg[base + 2] : 0;
  int v3 = (base + 3 < NN) ? deg[base + 3] : 0;
  int s = v0 + v1 + v2 + v3;
  sd[t] = s;
  __syncthreads();
  for (int off = 1; off < 256; off <<= 1) {
    int tmp = (t >= off) ? sd[t - off] : 0;
    __syncthreads();
    sd[t] += tmp;
    __syncthreads();
  }
  int excl = sd[t] - s;
  if (base + 0 < NN) row[base + 0] = excl;
  if (base + 1 < NN) row[base + 1] = excl + v0;
  if (base + 2 < NN) row[base + 2] = excl + v0 + v1;
  if (base + 3 < NN) row[base + 3] = excl + v0 + v1 + v2;
  if (t == 255) aux[b] = sd[t];
}

__global__ __launch_bounds__(256) void scan2_kernel(int* __restrict__ aux) {
  __shared__ int sd[256];
  int t = threadIdx.x;
  int v = (t < NBLK) ? aux[t] : 0;
  sd[t] = v;
  __syncthreads();
  for (int off = 1; off < 256; off <<= 1) {
    int tmp = (t >= off) ? sd[t - off] : 0;
    __syncthreads();
    sd[t] += tmp;
    __syncthreads();
  }
  if (t < NBLK) aux[t] = sd[t] - v;
}

__global__ __launch_bounds__(256) void scan3_kernel(
    int* __restrict__ row, const int* __restrict__ aux) {
  int i = blockIdx.x * 256 + threadIdx.x;
  if (i < NN) row[i] += aux[i >> 10];
  if (i == 0) row[NN] = NE;
}

__global__ __launch_bounds__(256) void fill_kernel(
    const int* __restrict__ ei, const int* __restrict__ row,
    int* __restrict__ cur, int* __restrict__ eidx) {
  const int* src = ei;
  const int* dst = ei + NE;
  int i = blockIdx.x * 256 + threadIdx.x;
  int n = gridDim.x * 256;
  for (int e = i; e < NE; e += n) {
    int d = dst[e];
    int p = atomicAdd(&cur[d], 1);
    eidx[row[d] + p] = src[e];
  }
}

// ============ conversions ============
// x (f32) -> A1 cols 128:256 (bf16)
__global__ __launch_bounds__(256) void conv_x(
    const float* __restrict__ x, unsigned short* __restrict__ A1) {
  int i = blockIdx.x * 256 + threadIdx.x;  // float4 groups
  if (i >= NN * 32) return;
  int n = i >> 5, k4 = i & 31;
  float4 v = ((const float4*)(x + (size_t)n * 128))[k4];
  ushort4 o;
  o.x = f2b(v.x); o.y = f2b(v.y); o.z = f2b(v.z); o.w = f2b(v.w);
  ((ushort4*)(A1 + (size_t)n * 256 + 128))[k4] = o;
}

// concat + convert weights: W1b[256][256]=[W1l|W1r], W2b[256][512]=[W2l|W2r],
// Wf1b[128][256]=Wf1
__global__ __launch_bounds__(256) void conv_w(
    const float* __restrict__ W1l, const float* __restrict__ W1r,
    const float* __restrict__ W2l, const float* __restrict__ W2r,
    const float* __restrict__ Wf1,
    unsigned short* __restrict__ W1b, unsigned short* __restrict__ W2b,
    unsigned short* __restrict__ Wf1b) {
  int i = blockIdx.x * 256 + threadIdx.x;  // vec4 id
  const float* srcp;
  unsigned short* dstp;
  if (i < 16384) {                     // W1b: 256x256
    int e = i * 4, j = e >> 8, k = e & 255;
    srcp = (k < 128) ? (W1l + (size_t)j * 128 + k) : (W1r + (size_t)j * 128 + (k - 128));
    dstp = W1b + e;
  } else if (i < 49152) {              // W2b: 256x512
    int e = (i - 16384) * 4, j = e >> 9, k = e & 511;
    srcp = (k < 256) ? (W2l + (size_t)j * 256 + k) : (W2r + (size_t)j * 256 + (k - 256));
    dstp = W2b + e;
  } else if (i < 57344) {              // Wf1b: flat copy 32768 elems
    int e = (i - 49152) * 4;
    srcp = Wf1 + e;
    dstp = Wf1b + e;
  } else return;
  float4 v = *(const float4*)srcp;
  ushort4 o;
  o.x = f2b(v.x); o.y = f2b(v.y); o.z = f2b(v.z); o.w = f2b(v.w);
  *(ushort4*)dstp = o;
}

// ============ aggregation via CSR gather ============
// mean of x-half of A1 rows (bf16, 128 wide) -> A1 cols 0:128
__global__ __launch_bounds__(256) void agg1_csr(
    unsigned short* __restrict__ A1, const int* __restrict__ row,
    const int* __restrict__ eidx) {
  int lane = threadIdx.x & 63;
  int n = (blockIdx.x * 256 + threadIdx.x) >> 6;
  if (n >= NN) return;
  int r0 = row[n], r1 = row[n + 1];
  float ax = 0.f, ay = 0.f;
  int e = r0;
  for (; e + 1 < r1; e += 2) {
    int s0 = eidx[e], s1 = eidx[e + 1];
    ushort2 a = ((const ushort2*)(A1 + (size_t)s0 * 256 + 128))[lane];
    ushort2 b = ((const ushort2*)(A1 + (size_t)s1 * 256 + 128))[lane];
    ax += b2f(a.x) + b2f(b.x);
    ay += b2f(a.y) + b2f(b.y);
  }
  if (e < r1) {
    int s0 = eidx[e];
    ushort2 a = ((const ushort2*)(A1 + (size_t)s0 * 256 + 128))[lane];
    ax += b2f(a.x);
    ay += b2f(a.y);
  }
  float inv = 1.0f / (float)max(r1 - r0, 1);
  ushort2 o;
  o.x = f2b(ax * inv);
  o.y = f2b(ay * inv);
  ((ushort2*)(A1 + (size_t)n * 256))[lane] = o;
}

// mean of h1-half of A2 rows (bf16, 256 wide) -> A2 cols 0:256
__global__ __launch_bounds__(256) void agg2_csr(
    unsigned short* __restrict__ A2, const int* __restrict__ row,
    const int* __restrict__ eidx) {
  int lane = threadIdx.x & 63;
  int n = (blockIdx.x * 256 + threadIdx.x) >> 6;
  if (n >= NN) return;
  int r0 = row[n], r1 = row[n + 1];
  float4 acc = make_float4(0.f, 0.f, 0.f, 0.f);
  int e = r0;
  for (; e + 1 < r1; e += 2) {
    int s0 = eidx[e], s1 = eidx[e + 1];
    ushort4 a = ((const ushort4*)(A2 + (size_t)s0 * 512 + 256))[lane];
    ushort4 b = ((const ushort4*)(A2 + (size_t)s1 * 512 + 256))[lane];
    acc.x += b2f(a.x) + b2f(b.x);
    acc.y += b2f(a.y) + b2f(b.y);
    acc.z += b2f(a.z) + b2f(b.z);
    acc.w += b2f(a.w) + b2f(b.w);
  }
  if (e < r1) {
    int s0 = eidx[e];
    ushort4 a = ((const ushort4*)(A2 + (size_t)s0 * 512 + 256))[lane];
    acc.x += b2f(a.x);
    acc.y += b2f(a.y);
    acc.z += b2f(a.z);
    acc.w += b2f(a.w);
  }
  float inv = 1.0f / (float)max(r1 - r0, 1);
  ushort4 o;
  o.x = f2b(acc.x * inv);
  o.y = f2b(acc.y * inv);
  o.z = f2b(acc.z * inv);
  o.w = f2b(acc.w * inv);
  ((ushort4*)(A2 + (size_t)n * 512))[lane] = o;
}

// ============ unified MFMA GEMM ============
// C[MPAD x NCOLTILE*128] = A(bf16, pitch APITCH) @ Wb(bf16,[ncols][K])^T
// tile 128x128, BK=64, 4 waves each 32 rows x 128 cols.
// LDS layout (per 64-k step): elem ((rep*8 + kb)*16 + r16)*8  (fragment-major)
// EPI 0: ELU(acc + bias[col]) -> bf16 Hout[row*HPITCH + HOFF + col]
// EPI 1: out[row] = sum_col relu(acc + bias[col]) * w2[col] + bf2
template <int K, int APITCH, int EPI>
__global__ __launch_bounds__(256) void gemm_kernel(
    const unsigned short* __restrict__ A, const unsigned short* __restrict__ Wb,
    const float* __restrict__ bias, const float* __restrict__ w2,
    const float* __restrict__ bf2p,
    unsigned short* __restrict__ Hout, int HPITCH, int HOFF,
    float* __restrict__ out) {
  __shared__ unsigned short lA[2][8192];
  __shared__ unsigned short lB[2][8192];
  int tid = threadIdx.x;
  int w = tid >> 6, lane = tid & 63;
  int lhi = lane >> 4, llo = lane & 15;
  int m0 = blockIdx.x * 128;
  int c0 = blockIdx.y * 128;
  int fb = lhi * 128 + llo * 8;  // fragment base elem offset

  f32x4 acc0[8], acc1[8];
#pragma unroll
  for (int n = 0; n < 8; ++n) { acc0[n] = (f32x4)0.f; acc1[n] = (f32x4)0.f; }

#define STAGE(buf, k0)                                                          \
  do {                                                                          \
    _Pragma("unroll")                                                           \
    for (int i = 0; i < 4; ++i) {                                               \
      int c = w * 4 + i;                                                        \
      int linear = c * 64 + lane;                                               \
      int r16 = linear & 15, kb = (linear >> 4) & 7, rep = linear >> 7;         \
      const unsigned short* ga =                                                \
          A + (size_t)(m0 + rep * 16 + r16) * APITCH + (k0) + kb * 8;           \
      gload_lds16(ga, &lA[buf][c * 512]);                                       \
      const unsigned short* gb =                                                \
          Wb + (size_t)(c0 + rep * 16 + r16) * K + (k0) + kb * 8;               \
      gload_lds16(gb, &lB[buf][c * 512]);                                       \
    }                                                                           \
  } while (0)

  constexpr int NSTEP = K / 64;
  STAGE(0, 0);
  asm volatile("s_waitcnt vmcnt(0)");
  __syncthreads();
  int cur = 0;
  for (int t = 0; t < NSTEP; ++t) {
    if (t + 1 < NSTEP) STAGE(cur ^ 1, (t + 1) * 64);
#pragma unroll
    for (int kc = 0; kc < 2; ++kc) {
      i32x4 a0 = *(const i32x4*)&lA[cur][(w * 2 + 0) * 1024 + kc * 512 + fb];
      i32x4 a1 = *(const i32x4*)&lA[cur][(w * 2 + 1) * 1024 + kc * 512 + fb];
#pragma unroll
      for (int n = 0; n < 8; ++n) {
        i32x4 b = *(const i32x4*)&lB[cur][n * 1024 + kc * 512 + fb];
        acc0[n] = mfma16(a0, b, acc0[n]);
        acc1[n] = mfma16(a1, b, acc1[n]);
      }
    }
    asm volatile("s_waitcnt vmcnt(0)");
    __syncthreads();
    cur ^= 1;
  }
#undef STAGE
  asm volatile("s_nop 7\n\ts_nop 7");  // MFMA -> VALU read hazard

  if constexpr (EPI == 0) {
    float bv[8];
#pragma unroll
    for (int n = 0; n < 8; ++n) bv[n] = bias[c0 + n * 16 + llo];
#pragma unroll
    for (int mi = 0; mi < 2; ++mi) {
#pragma unroll
      for (int n = 0; n < 8; ++n) {
        f32x4 av = mi ? acc1[n] : acc0[n];
#pragma unroll
        for (int r = 0; r < 4; ++r) {
          int R = m0 + (w * 2 + mi) * 16 + lhi * 4 + r;
          float v = elu(av[r] + bv[n]);
          Hout[(size_t)R * HPITCH + HOFF + c0 + n * 16 + llo] = f2b(v);
        }
      }
    }
  } else {
    float b1v[8], w2v[8];
#pragma unroll
    for (int n = 0; n < 8; ++n) {
      b1v[n] = bias[n * 16 + llo];
      w2v[n] = w2[n * 16 + llo];
    }
    float bf2v = bf2p[0];
#pragma unroll
    for (int mi = 0; mi < 2; ++mi) {
#pragma unroll
      for (int r = 0; r < 4; ++r) {
        float s = 0.f;
#pragma unroll
        for (int n = 0; n < 8; ++n) {
          f32x4 av = mi ? acc1[n] : acc0[n];
          s += fmaxf(av[r] + b1v[n], 0.f) * w2v[n];
        }
        s += __shfl_xor(s, 1);
        s += __shfl_xor(s, 2);
        s += __shfl_xor(s, 4);
        s += __shfl_xor(s, 8);
        int R = m0 + (w * 2 + mi) * 16 + lhi * 4 + r;
        if (llo == 0 && R < NN) out[R] = s + bf2v;
      }
    }
  }
}

extern "C" void kernel_launch(void* const* d_in, const int* in_sizes, int n_in,
                              void* d_out, int out_size, void* d_ws, size_t ws_size,
                              hipStream_t stream) {
  const float* x   = (const float*)d_in[0];
  const int*   ei  = (const int*)d_in[1];
  const float* W1l = (const float*)d_in[2];
  const float* b1  = (const float*)d_in[3];
  const float* W1r = (const float*)d_in[4];
  const float* W2l = (const float*)d_in[5];
  const float* b2  = (const float*)d_in[6];
  const float* W2r = (const float*)d_in[7];
  const float* Wf1 = (const float*)d_in[8];
  const float* bf1 = (const float*)d_in[9];
  const float* Wf2 = (const float*)d_in[10];
  const float* bf2 = (const float*)d_in[11];
  float* out = (float*)d_out;

  char* ws = (char*)d_ws;
  size_t o = 0;
  int* deg = (int*)(ws + o); o += 400384;   // zeroed each call
  int* cur = (int*)(ws + o); o += 400384;   // zeroed each call
  size_t zero_bytes = o;
  int* row  = (int*)(ws + o); o += 400640;  // NN+1
  int* aux  = (int*)(ws + o); o += 4096;
  int* eidx = (int*)(ws + o); o += 2400000;
  unsigned short* A1 = (unsigned short*)(ws + o); o += (size_t)MPAD * 256 * 2; // [mean1|x]
  unsigned short* A2 = (unsigned short*)(ws + o); o += (size_t)MPAD * 512 * 2; // [mean2|h1]
  unsigned short* h2 = (unsigned short*)(ws + o); o += (size_t)MPAD * 256 * 2;
  unsigned short* W1b  = (unsigned short*)(ws + o); o += 131072;
  unsigned short* W2b  = (unsigned short*)(ws + o); o += 262144;
  unsigned short* Wf1b = (unsigned short*)(ws + o); o += 65536;
  // total ~199.4 MiB

  hipMemsetAsync(d_ws, 0, zero_bytes, stream);

  // CSR build (deterministic per call)
  hist_kernel<<<2048, 256, 0, stream>>>(ei, deg);
  scan1_kernel<<<NBLK, 256, 0, stream>>>(deg, row, aux);
  scan2_kernel<<<1, 256, 0, stream>>>(aux);
  scan3_kernel<<<(NN + 255) / 256, 256, 0, stream>>>(row, aux);
  fill_kernel<<<2048, 256, 0, stream>>>(ei, row, cur, eidx);

  // convert inputs/weights to bf16 operand layouts
  conv_x<<<(NN * 32 + 255) / 256, 256, 0, stream>>>(x, A1);
  conv_w<<<224, 256, 0, stream>>>(W1l, W1r, W2l, W2r, Wf1, W1b, W2b, Wf1b);

  // pipeline
  agg1_csr<<<25000, 256, 0, stream>>>(A1, row, eidx);
  gemm_kernel<256, 256, 0><<<dim3(MPAD / 128, 2), 256, 0, stream>>>(
      A1, W1b, b1, nullptr, nullptr, A2, 512, 256, nullptr);
  agg2_csr<<<25000, 256, 0, stream>>>(A2, row, eidx);
  gemm_kernel<512, 512, 0><<<dim3(MPAD / 128, 2), 256, 0, stream>>>(
      A2, W2b, b2, nullptr, nullptr, h2, 256, 0, nullptr);
  gemm_kernel<256, 256, 1><<<dim3(MPAD / 128, 1), 256, 0, stream>>>(
      h2, Wf1b, bf1, Wf2, bf2, nullptr, 0, 0, out);
}